// Round 12
// baseline (148.928 us; speedup 1.0000x reference)
//
#include <hip/hip_runtime.h>
#include <math.h>
#include <stdint.h>

#define B_ 16
#define D_ 1024
#define T_ 4096
#define CS_ 1024
#define CD_ 8

// ---------- numpy-mimicking fp32 helpers ----------
__device__ __forceinline__ float f_tree8(const float r[8]) {
  return __fadd_rn(
      __fadd_rn(__fadd_rn(r[0], r[1]), __fadd_rn(r[2], r[3])),
      __fadd_rn(__fadd_rn(r[4], r[5]), __fadd_rn(r[6], r[7])));
}
__device__ __forceinline__ float f_sumsq8(const float x[8]) {
  float s[8];
#pragma unroll
  for (int k = 0; k < 8; ++k) s[k] = __fmul_rn(x[k], x[k]);
  return f_tree8(s);
}

// async global->LDS, 16B per lane, dest = wave-uniform base + lane*16
__device__ __forceinline__ void gl_lds16(const void* g, void* l) {
  __builtin_amdgcn_global_load_lds(
      (const __attribute__((address_space(1))) void*)g,
      (__attribute__((address_space(3))) void*)l, 16, 0, 0);
}
template <int N>
__device__ __forceinline__ void vmwait() {
  asm volatile("s_waitcnt vmcnt(%0)" ::"n"(N) : "memory");
}

// ---------- setup: normalize W_in, W_out, codebook; pack tables ----------
// ws layout:
//   WTd  : double[1024][8]   (W_in^T, fp32-rounded widened to f64)  @ 0      (65536 B)
//   cb16 : float [1024][16]  ({cbn[8], scb, pad})                   @ 65536  (65536 B)
//   wo16 : float [1024][16]  ({woutn[8], b_out, pad})               @ 131072 (65536 B)
//   lossp: float [512]                                              @ 196608 (2048 B)
__global__ __launch_bounds__(1024) void vq_setup(
    const float* __restrict__ cb, const float* __restrict__ g_in,
    const float* __restrict__ v_in, const float* __restrict__ g_out,
    const float* __restrict__ v_out, const float* __restrict__ b_out,
    double* __restrict__ WTd, float* __restrict__ cb16,
    float* __restrict__ wo16) {
  __shared__ float sv[8 * 1024];
  __shared__ float leafs[64];
  __shared__ float den[8];
  const int tid = threadIdx.x;

  for (int i = tid; i < 8 * 1024; i += 1024) sv[i] = v_in[i];
  __syncthreads();

  // numpy pairwise_sum(1024): 8 leaf blocks of 128 (8-accumulator pattern),
  // combined with the same binary tree as tree8.
  if (tid < 64) {
    const int c = tid >> 3, l = tid & 7;
    const float* a = sv + c * 1024 + l * 128;
    float r[8];
#pragma unroll
    for (int k = 0; k < 8; ++k) r[k] = __fmul_rn(a[k], a[k]);
    for (int i = 8; i < 128; i += 8) {
#pragma unroll
      for (int k = 0; k < 8; ++k)
        r[k] = __fadd_rn(r[k], __fmul_rn(a[i + k], a[i + k]));
    }
    leafs[c * 8 + l] = f_tree8(r);
  }
  __syncthreads();
  if (tid < 8) {
    const float* L = leafs + tid * 8;
    float lr[8];
#pragma unroll
    for (int k = 0; k < 8; ++k) lr[k] = L[k];
    const float s = f_tree8(lr);
    den[tid] = fmaxf(__fsqrt_rn(s), 1e-12f);
  }
  __syncthreads();

  if (tid < 1024) {
#pragma unroll
    for (int c = 0; c < 8; ++c) {
      const float w = __fdiv_rn(__fmul_rn(g_in[c], sv[c * 1024 + tid]), den[c]);
      WTd[tid * 8 + c] = (double)w;
    }
    {
      const float* cr = cb + tid * 8;
      float q[8];
#pragma unroll
      for (int c = 0; c < 8; ++c) q[c] = cr[c];
      const float nn = f_sumsq8(q);
      const float dd = fmaxf(__fsqrt_rn(nn), 1e-12f);
      float qn[8];
#pragma unroll
      for (int c = 0; c < 8; ++c) {
        qn[c] = __fdiv_rn(q[c], dd);
        cb16[tid * 16 + c] = qn[c];
      }
      cb16[tid * 16 + 8] = f_sumsq8(qn);
#pragma unroll
      for (int c = 9; c < 16; ++c) cb16[tid * 16 + c] = 0.f;
    }
    {
      const float* vr = v_out + tid * 8;
      float w[8];
#pragma unroll
      for (int c = 0; c < 8; ++c) w[c] = vr[c];
      const float n2 = f_sumsq8(w);
      const float d2 = fmaxf(__fsqrt_rn(n2), 1e-12f);
      const float go = g_out[tid];
#pragma unroll
      for (int c = 0; c < 8; ++c)
        wo16[tid * 16 + c] = __fdiv_rn(__fmul_rn(go, w[c]), d2);
      wo16[tid * 16 + 8] = b_out[tid];
#pragma unroll
      for (int c = 9; c < 16; ++c) wo16[tid * 16 + c] = 0.f;
    }
  }
}

// ---------- main kernel (R10 + global_load_lds z-ring in P1) ----------
// Grid: 512 blocks x 1024 threads (16 waves). Block owns 128 consecutive t
// of one b; each LANE owns 2 consecutive t. Wave q covers the same 128 t
// but d/code SLICE [q*64, (q+1)*64).
// R12 (=R11 fixed): P1 z loads go global->LDS via global_load_lds into a
// PRIVATE 4 KB ring per wave (2 chunks x 2 KB; chunk = 4 d-rows, 2 insts
// of 16B/lane). vmcnt-counted waits (2, tail 0) keep ~2 KB/wave in flight
// with ZERO VGPR cost -- R10's VGPR=32 showed the register file couldn't
// hold both the f64 accumulators and a prefetch under the 64-VGPR cap.
// Ring lives in accb (idle during P1); barrier before combine reuse.
__global__ __launch_bounds__(1024, 8) void vq_main(
    const float* __restrict__ z, const float* __restrict__ cbraw,
    const float* __restrict__ b_in, const double* __restrict__ WTd,
    const float* __restrict__ cb16, const float* __restrict__ wo16,
    float* __restrict__ out, float* __restrict__ oidx,
    float* __restrict__ lossp) {
  __shared__ double accb[8704];  // 68 KB: z-ring / partials / candidates
  const int tid = threadIdx.x;
  const int q0 = __builtin_amdgcn_readfirstlane(tid >> 6);  // wave 0..15
  const int tl = tid & 63;
  const int blk = blockIdx.x;  // 512 = 16 b * 32 tiles
  const int b = blk >> 5;
  const int tile = blk & 31;
  const int t0 = tile * 128 + tl * 2;  // this lane's t-pair

  // ---- phase 1: partial z_e in f64 over this wave's 64-d slice ----
  // z-row r (r=0..63): 128 t * 4B = 512B. One gl_lds inst stages 2 rows
  // (1 KB): lanes 0-31 -> row, lanes 32-63 -> row+1; lane%32 picks 16B
  // (4 consecutive t). Chunk = 4 rows = 2 insts = 2 KB; ring of 2 chunks.
  const double* wd = WTd + (size_t)q0 * 512;  // uniform -> s_load
  const char* gz = (const char*)(z +
      ((size_t)(b * D_ + q0 * 64 + (tl >> 5))) * T_ + tile * 128 +
      (tl & 31) * 4);
  char* ring = (char*)accb + q0 * 4096;  // wave-private 4 KB

  double acc0[8], acc1[8];
#pragma unroll
  for (int c = 0; c < 8; ++c) { acc0[c] = 0.0; acc1[c] = 0.0; }

  // prologue: issue chunks 0 and 1 (4 insts outstanding)
#pragma unroll
  for (int cc = 0; cc < 2; ++cc) {
#pragma unroll
    for (int i = 0; i < 2; ++i) {
      gl_lds16(gz + (size_t)(cc * 4 + 2 * i) * T_ * 4,
               ring + cc * 2048 + i * 1024);
    }
  }

#pragma unroll
  for (int c = 0; c < 16; ++c) {
    // wait for chunk c (keep next chunk's 2 loads in flight; drain at tail)
    if (c < 15) vmwait<2>(); else vmwait<0>();
    char* slot = ring + (c & 1) * 2048;
    // consume 4 rows: z from LDS (8B/lane, 2-way alias = free), W via
    // s_load batched by the compiler, FMA rows ascending / channels inner
    // (bit-identical order to R10)
#pragma unroll
    for (int p = 0; p < 4; ++p) {
      const float2 zv = *(const float2*)(slot + p * 512 + tl * 8);
      const double* w = wd + (size_t)(4 * c + p) * 8;
      const double zx = (double)zv.x, zy = (double)zv.y;
#pragma unroll
      for (int ch = 0; ch < 8; ++ch) {
        acc0[ch] = fma(zx, w[ch], acc0[ch]);
        acc1[ch] = fma(zy, w[ch], acc1[ch]);
      }
    }
    // issue chunk c+2 into the slot just consumed (fence: keep the issue
    // below the ds_reads above)
    asm volatile("" ::: "memory");
    if (c < 14) {
#pragma unroll
      for (int i = 0; i < 2; ++i) {
        gl_lds16(gz + (size_t)((c + 2) * 4 + 2 * i) * T_ * 4,
                 slot + i * 1024);
      }
    }
  }
  __syncthreads();  // all waves done with rings before combine reuses accb

  // ---- 16-slice f64 combine: wave 0 reduces (ascending slice order),
  //      result broadcast via disjoint LDS ----
  double2* accb2 = (double2*)accb;       // partials: [0, 4096) double2
  double2* totb = accb2 + 4096;          // tot: [4096, 4352) double2
  double tot0[8], tot1[8];
#pragma unroll
  for (int half = 0; half < 2; ++half) {
    const int c0 = half * 4;
#pragma unroll
    for (int c = 0; c < 4; ++c) {
      double2 v; v.x = acc0[c0 + c]; v.y = acc1[c0 + c];
      accb2[c * 1024 + tid] = v;
    }
    __syncthreads();
    if (tid < 64) {
#pragma unroll
      for (int c = 0; c < 4; ++c) {
        const double2* row = accb2 + c * 1024 + tl;
        double2 s = row[0];
#pragma unroll
        for (int qq = 1; qq < 16; ++qq) {
          const double2 v = row[qq * 64];
          s.x = s.x + v.x;  // ascending slice order
          s.y = s.y + v.y;
        }
        totb[c * 64 + tl] = s;
      }
    }
    __syncthreads();
#pragma unroll
    for (int c = 0; c < 4; ++c) {
      const double2 s = totb[c * 64 + tl];
      tot0[c0 + c] = s.x; tot1[c0 + c] = s.y;
    }
  }

  // materialize fp32 z_e (+ b_in), normalize (numpy-mimicked), per t
  float e0[8], e1[8], en0[8], en1[8];
#pragma unroll
  for (int c = 0; c < 8; ++c) {
    e0[c] = __fadd_rn((float)tot0[c], b_in[c]);
    e1[c] = __fadd_rn((float)tot1[c], b_in[c]);
  }
  const float n20 = f_sumsq8(e0), n21 = f_sumsq8(e1);
  const float dn0 = fmaxf(__fsqrt_rn(n20), 1e-12f);
  const float dn1 = fmaxf(__fsqrt_rn(n21), 1e-12f);
#pragma unroll
  for (int c = 0; c < 8; ++c) {
    en0[c] = __fdiv_rn(e0[c], dn0);
    en1[c] = __fdiv_rn(e1[c], dn1);
  }
  const float s_enc0 = f_sumsq8(en0), s_enc1 = f_sumsq8(en1);

  // ---- phase 2: nearest code over this wave's 64-code slice ----
  const int j0 = q0 * 64;
  float best0 = INFINITY, best1 = INFINITY;
  int bj0 = j0, bj1 = j0;
  {
    const float* cbq = cb16 + (size_t)j0 * 16;  // uniform -> s_load
#pragma unroll 4
    for (int jj = 0; jj < 64; ++jj) {
      const float* row = cbq + jj * 16;
      const float4 lo = *(const float4*)(row);
      const float4 hi = *(const float4*)(row + 4);
      const float sc = row[8];
      float d0 = 0.f, d1 = 0.f;
      d0 = fmaf(en0[0], lo.x, d0); d1 = fmaf(en1[0], lo.x, d1);
      d0 = fmaf(en0[1], lo.y, d0); d1 = fmaf(en1[1], lo.y, d1);
      d0 = fmaf(en0[2], lo.z, d0); d1 = fmaf(en1[2], lo.z, d1);
      d0 = fmaf(en0[3], lo.w, d0); d1 = fmaf(en1[3], lo.w, d1);
      d0 = fmaf(en0[4], hi.x, d0); d1 = fmaf(en1[4], hi.x, d1);
      d0 = fmaf(en0[5], hi.y, d0); d1 = fmaf(en1[5], hi.y, d1);
      d0 = fmaf(en0[6], hi.z, d0); d1 = fmaf(en1[6], hi.z, d1);
      d0 = fmaf(en0[7], hi.w, d0); d1 = fmaf(en1[7], hi.w, d1);
      const float dist0 =
          __fadd_rn(__fsub_rn(s_enc0, __fmul_rn(2.0f, d0)), sc);
      const float dist1 =
          __fadd_rn(__fsub_rn(s_enc1, __fmul_rn(2.0f, d1)), sc);
      if (dist0 < best0) { best0 = dist0; bj0 = j0 + jj; }
      if (dist1 < best1) { best1 = dist1; bj1 = j0 + jj; }
    }
  }

  // ---- candidate combine: wave 0 scans (ascending qq, strict <), writes
  //      idx, broadcasts winners via ibuf for P3 ----
  float* distf0 = (float*)accb;                  // 1024 f32
  int* candj0 = (int*)((char*)accb + 4096);      // 1024 i32
  float* distf1 = (float*)((char*)accb + 8192);  // 1024 f32
  int* candj1 = (int*)((char*)accb + 12288);     // 1024 i32
  int* ibuf = (int*)((char*)accb + 16384);       // 128 i32
  distf0[tid] = best0; candj0[tid] = bj0;
  distf1[tid] = best1; candj1[tid] = bj1;
  __syncthreads();

  if (tid < 64) {
    float bd0 = distf0[tl], bd1 = distf1[tl];
    int ci0 = candj0[tl], ci1 = candj1[tl];
#pragma unroll
    for (int qq = 1; qq < 16; ++qq) {
      float dd = distf0[qq * 64 + tl];
      int jj = candj0[qq * 64 + tl];
      if (dd < bd0) { bd0 = dd; ci0 = jj; }  // strict <: low slice wins
      dd = distf1[qq * 64 + tl];
      jj = candj1[qq * 64 + tl];
      if (dd < bd1) { bd1 = dd; ci1 = jj; }
    }
    ibuf[tl] = ci0; ibuf[64 + tl] = ci1;
    float2 iv; iv.x = (float)ci0; iv.y = (float)ci1;
    *(float2*)(oidx + (size_t)b * T_ + t0) = iv;
  }
  __syncthreads();
  const int bi0 = ibuf[tl];
  const int bi1 = ibuf[64 + tl];

  // raw codebook rows for loss + back-projection (divergent 32B gathers)
  float cq0[8], cq1[8];
  {
    const float* cp0 = cbraw + (size_t)bi0 * 8;
    const float* cp1 = cbraw + (size_t)bi1 * 8;
#pragma unroll
    for (int c = 0; c < 8; ++c) { cq0[c] = cp0[c]; cq1[c] = cp1[c]; }
  }

  // ---- loss partial (wave 0 only; all waves hold identical e, cq) ----
  if (tid < 64) {
    float lsum = 0.f;
#pragma unroll
    for (int c = 0; c < 8; ++c) {
      const float df0 = __fsub_rn(e0[c], cq0[c]);
      lsum = fmaf(df0, df0, lsum);
    }
#pragma unroll
    for (int c = 0; c < 8; ++c) {
      const float df1 = __fsub_rn(e1[c], cq1[c]);
      lsum = fmaf(df1, df1, lsum);
    }
#pragma unroll
    for (int off = 32; off > 0; off >>= 1)
      lsum += __shfl_down(lsum, off, 64);
    if (tl == 0) lossp[blk] = lsum;
  }

  // ---- phase 3: out[b,d,{t0,t0+1}] over this wave's 64-d slice ----
  float2* op2 =
      (float2*)(out + ((size_t)b * D_ + (size_t)q0 * 64) * T_ + t0);
  const float* woq = wo16 + (size_t)q0 * 1024;  // uniform -> s_load
#pragma unroll 4
  for (int d = 0; d < 64; ++d) {
    const float* row = woq + d * 16;
    const float4 lo = *(const float4*)(row);
    const float4 hi = *(const float4*)(row + 4);
    const float bo = row[8];
    float d0 = 0.f, d1 = 0.f;
    d0 = fmaf(cq0[0], lo.x, d0); d1 = fmaf(cq1[0], lo.x, d1);
    d0 = fmaf(cq0[1], lo.y, d0); d1 = fmaf(cq1[1], lo.y, d1);
    d0 = fmaf(cq0[2], lo.z, d0); d1 = fmaf(cq1[2], lo.z, d1);
    d0 = fmaf(cq0[3], lo.w, d0); d1 = fmaf(cq1[3], lo.w, d1);
    d0 = fmaf(cq0[4], hi.x, d0); d1 = fmaf(cq1[4], hi.x, d1);
    d0 = fmaf(cq0[5], hi.y, d0); d1 = fmaf(cq1[5], hi.y, d1);
    d0 = fmaf(cq0[6], hi.z, d0); d1 = fmaf(cq1[6], hi.z, d1);
    d0 = fmaf(cq0[7], hi.w, d0); d1 = fmaf(cq1[7], hi.w, d1);
    float2 ov; ov.x = __fadd_rn(d0, bo); ov.y = __fadd_rn(d1, bo);
    op2[(size_t)d * (T_ / 2)] = ov;
  }
}

// ---------- finalize loss ----------
__global__ __launch_bounds__(64) void vq_fin(const float* __restrict__ lossp,
                                             float* __restrict__ oloss) {
  const int tid = threadIdx.x;
  if (tid < B_) {
    float s = 0.f;
    for (int i = 0; i < 32; ++i) s += lossp[tid * 32 + i];
    oloss[tid] = s * (1.25f / 32768.0f);
  }
}

extern "C" void kernel_launch(void* const* d_in, const int* in_sizes, int n_in,
                              void* d_out, int out_size, void* d_ws,
                              size_t ws_size, hipStream_t stream) {
  (void)in_sizes; (void)n_in; (void)out_size; (void)ws_size;
  const float* z = (const float*)d_in[0];
  const float* cb = (const float*)d_in[1];
  const float* g_in = (const float*)d_in[2];
  const float* v_in = (const float*)d_in[3];
  const float* b_in = (const float*)d_in[4];
  const float* g_out = (const float*)d_in[5];
  const float* v_out = (const float*)d_in[6];
  const float* b_out = (const float*)d_in[7];
  float* out = (float*)d_out;

  char* ws = (char*)d_ws;
  double* WTd = (double*)ws;              // 65536 B
  float* cb16 = (float*)(ws + 65536);     // 65536 B
  float* wo16 = (float*)(ws + 131072);    // 65536 B
  float* lossp = (float*)(ws + 196608);   // 2048 B

  float* oidx = out + (size_t)B_ * D_ * T_;
  float* oloss = oidx + (size_t)B_ * T_;

  vq_setup<<<1, 1024, 0, stream>>>(cb, g_in, v_in, g_out, v_out, b_out, WTd,
                                   cb16, wo16);
  vq_main<<<512, 1024, 0, stream>>>(z, cb, b_in, WTd, cb16, wo16, out, oidx,
                                    lossp);
  vq_fin<<<1, 64, 0, stream>>>(lossp, oloss);
}